// Round 9
// baseline (530.755 us; speedup 1.0000x reference)
//
#include <hip/hip_runtime.h>
#include <hip/hip_bf16.h>

typedef __bf16 bf16;
typedef __bf16 bf16x4 __attribute__((ext_vector_type(4)));
typedef __bf16 bf16x8 __attribute__((ext_vector_type(8)));
typedef float floatx4 __attribute__((ext_vector_type(4)));

#define MFMA16(a, b, c) __builtin_amdgcn_mfma_f32_16x16x32_bf16(a, b, c, 0, 0, 0)

// ---------------- constants ----------------
#define BB   4
#define TT   1024
#define SS   1024
#define DMOD 1024
#define NH   16
#define DH   64
#define HID  4096
#define MTOT (BB * TT)

__device__ __forceinline__ float loadf(const bf16* p)  { return (float)*p; }
__device__ __forceinline__ float loadf(const float* p) { return *p; }

// async global->LDS, 16B per lane; LDS dest = wave-uniform base + lane*16
__device__ __forceinline__ void gll16(const bf16* g, bf16* l) {
    __builtin_amdgcn_global_load_lds(
        (const __attribute__((address_space(1))) void*)g,
        (__attribute__((address_space(3))) void*)l, 16, 0, 0);
}

// XCD-chunked swizzle (T1): each XCD gets a contiguous chunk of the linear
// grid (y-major). Bijective iff nwg % 8 == 0 (all our grids satisfy this).
__device__ __forceinline__ void xcd_swizzle2d(int& bx, int& by) {
    const int gx  = gridDim.x;
    const int nwg = gx * gridDim.y;
    const int lin = blockIdx.y * gx + blockIdx.x;
    const int q   = nwg >> 3;
    const int swz = (lin & 7) * q + (lin >> 3);
    bx = swz % gx;
    by = swz / gx;
}

// ---------------- batched square transpose: fp32 W[1024][1024] -> bf16 WT ----------
struct TBatch { const float* src[8]; bf16* dst[8]; };

__global__ __launch_bounds__(256)
void transpose_sq_kernel(TBatch tb)
{
    __shared__ float t[64][65];
    const float* W = tb.src[blockIdx.z];
    bf16* WT = tb.dst[blockIdx.z];
    const int k0 = blockIdx.y * 64, n0 = blockIdx.x * 64;
    const int tid = threadIdx.x;
    const int r = tid >> 4, c = (tid & 15) * 4;
    #pragma unroll
    for (int i = 0; i < 4; ++i) {
        float4 v = *(const float4*)(W + (size_t)(k0 + i * 16 + r) * DMOD + n0 + c);
        t[i * 16 + r][c + 0] = v.x; t[i * 16 + r][c + 1] = v.y;
        t[i * 16 + r][c + 2] = v.z; t[i * 16 + r][c + 3] = v.w;
    }
    __syncthreads();
    #pragma unroll
    for (int i = 0; i < 4; ++i) {
        int n = i * 16 + r;
        bf16x4 o;
        #pragma unroll
        for (int j = 0; j < 4; ++j) o[j] = (bf16)t[c + j][n];
        *(bf16x4*)(WT + (size_t)(n0 + n) * DMOD + k0 + c) = o;
    }
}

// general transpose (for wh / wout)
__global__ __launch_bounds__(256)
void transpose_kernel(const float* __restrict__ W, bf16* __restrict__ WT, int K, int N)
{
    __shared__ float t[64][65];
    const int k0 = blockIdx.y * 64, n0 = blockIdx.x * 64;
    const int tid = threadIdx.x;
    const int r = tid >> 4, c = (tid & 15) * 4;
    #pragma unroll
    for (int i = 0; i < 4; ++i) {
        float4 v = *(const float4*)(W + (size_t)(k0 + i * 16 + r) * N + n0 + c);
        t[i * 16 + r][c + 0] = v.x; t[i * 16 + r][c + 1] = v.y;
        t[i * 16 + r][c + 2] = v.z; t[i * 16 + r][c + 3] = v.w;
    }
    __syncthreads();
    #pragma unroll
    for (int i = 0; i < 4; ++i) {
        int n = i * 16 + r;
        bf16x4 o;
        #pragma unroll
        for (int j = 0; j < 4; ++j) o[j] = (bf16)t[c + j][n];
        *(bf16x4*)(WT + (size_t)(n0 + n) * K + k0 + c) = o;
    }
}

// ---------------- bf16 sub-matrix transpose: in[4096][1024 cols](ldi) -> out[1024][4096]
__global__ __launch_bounds__(256)
void vtrans_kernel(const bf16* __restrict__ in, int ldi, bf16* __restrict__ out)
{
    __shared__ bf16 t[64][72];
    const int r0 = blockIdx.y * 64;   // M dim
    const int c0 = blockIdx.x * 64;   // col dim (1024)
    const int tid = threadIdx.x;
    const int rr = tid >> 3;          // 0..31
    const int c8 = (tid & 7) * 8;
    #pragma unroll
    for (int i = 0; i < 2; ++i) {
        int row = i * 32 + rr;
        bf16x8 v = *(const bf16x8*)(in + (size_t)(r0 + row) * ldi + c0 + c8);
        *(bf16x8*)(&t[row][c8]) = v;
    }
    __syncthreads();
    #pragma unroll
    for (int i = 0; i < 2; ++i) {
        int col = i * 32 + rr;
        bf16x8 v;
        #pragma unroll
        for (int j = 0; j < 8; ++j) v[j] = t[c8 + j][col];
        *(bf16x8*)(out + (size_t)(c0 + col) * MTOT + r0 + c8) = v;
    }
}

// ---------------- fp32 -> bf16 convert ----------------
__global__ __launch_bounds__(256)
void cvt_kernel(const float* __restrict__ in, bf16* __restrict__ out, int n4)
{
    int i = blockIdx.x * 256 + threadIdx.x;
    if (i < n4) {
        float4 v = ((const float4*)in)[i];
        bf16x4 o = { (bf16)v.x, (bf16)v.y, (bf16)v.z, (bf16)v.w };
        ((bf16x4*)out)[i] = o;
    }
}

// ---------------- bias concat: [bq1|bk1|bv1 | bk2|bv2] ----------------
__global__ __launch_bounds__(256)
void bias_concat_kernel(const float* bq1, const float* bk1, const float* bv1,
                        const float* bk2, const float* bv2, float* __restrict__ biasc)
{
    int i = blockIdx.x * 256 + threadIdx.x;   // 0..5119
    float v;
    if      (i < 1024) v = bq1[i];
    else if (i < 2048) v = bk1[i - 1024];
    else if (i < 3072) v = bv1[i - 2048];
    else if (i < 4096) v = bk2[i - 3072];
    else               v = bv2[i - 4096];
    if (i < 5120) biasc[i] = v;
}

// ------- GEMM 64x128: wide-N GEMMs (QKV/KV/FFN1). BN=128 keeps A-traffic at the
// 128²-tile level (r8 lesson: BN controls A-refetch); BM=64 cuts LDS to 48 KB ->
// 3 blocks/CU = 12 waves/CU for TLP latency hiding (r7 mechanism, m114).
template <int EPI, typename TR>
__global__ __launch_bounds__(256, 3)
void gemm64_kernel(const bf16* __restrict__ A, int lda, const bf16* __restrict__ B,
                   const float* __restrict__ bias, const TR* __restrict__ resid,
                   bf16* __restrict__ out, int M, int N, int K)
{
    __shared__ bf16 Al[2][64 * 64];
    __shared__ bf16 Bl[2][128 * 64];

    const int tid  = threadIdx.x;
    const int wave = tid >> 6;
    const int lane = tid & 63;
    const int l16  = lane & 15;
    const int quad = lane >> 4;
    int bx, by;
    xcd_swizzle2d(bx, by);
    const int bm   = by * 64;
    const int bn   = bx * 128;
    const int wm   = (wave >> 1) * 32;
    const int wn   = (wave & 1) * 64;
    const int lrow = lane >> 3;
    const int scol = ((lane & 7) ^ lrow) * 8;

    floatx4 acc[2][4] = {};
    const int ntk = K / 64;

    auto STAGE = [&](int kt, int buf) {
        const int k0 = kt * 64;
        #pragma unroll
        for (int i = 0; i < 2; ++i) {
            int r0 = wave * 16 + i * 8;
            gll16(A + (size_t)(bm + r0 + lrow) * lda + k0 + scol, &Al[buf][r0 * 64]);
        }
        #pragma unroll
        for (int i = 0; i < 4; ++i) {
            int r0 = (wave * 4 + i) * 8;
            gll16(B + (size_t)(bn + r0 + lrow) * K + k0 + scol, &Bl[buf][r0 * 64]);
        }
    };

    auto COMPUTE = [&](int buf) {
        #pragma unroll
        for (int ks = 0; ks < 2; ++ks) {
            bf16x8 af[2], bg[4];
            const int xo = ((ks * 4 + quad) ^ (l16 & 7)) * 8;
            #pragma unroll
            for (int mt = 0; mt < 2; ++mt)
                af[mt] = *(const bf16x8*)(&Al[buf][(wm + mt * 16 + l16) * 64 + xo]);
            #pragma unroll
            for (int nt = 0; nt < 4; ++nt)
                bg[nt] = *(const bf16x8*)(&Bl[buf][(wn + nt * 16 + l16) * 64 + xo]);
            #pragma unroll
            for (int mt = 0; mt < 2; ++mt)
                #pragma unroll
                for (int nt = 0; nt < 4; ++nt)
                    acc[mt][nt] = MFMA16(af[mt], bg[nt], acc[mt][nt]);
        }
    };

    STAGE(0, 0);
    asm volatile("s_waitcnt vmcnt(0)" ::: "memory");
    __builtin_amdgcn_s_barrier();

    int cur = 0;
    for (int t = 0; t < ntk - 1; ++t) {
        STAGE(t + 1, cur ^ 1);
        COMPUTE(cur);
        asm volatile("s_waitcnt vmcnt(0) lgkmcnt(0)" ::: "memory");
        __builtin_amdgcn_s_barrier();
        cur ^= 1;
    }
    COMPUTE(cur);

    #pragma unroll
    for (int mt = 0; mt < 2; ++mt) {
        int row0 = bm + wm + mt * 16 + quad * 4;
        #pragma unroll
        for (int nt = 0; nt < 4; ++nt) {
            int col = bn + wn + nt * 16 + l16;
            float bv = bias[col];
            #pragma unroll
            for (int r = 0; r < 4; ++r) {
                float v = acc[mt][nt][r] + bv;
                size_t idx = (size_t)(row0 + r) * N + col;
                if (EPI == 1) v = fmaxf(v, 0.0f);
                if (EPI == 2) v += loadf(resid + idx);
                out[idx] = (bf16)v;
            }
        }
    }
}

// ------- GEMM 64x64: N=1024 GEMMs + FFN2 (r7-proven: 4 blocks/CU TLP) -------
template <int EPI, typename TR>
__global__ __launch_bounds__(256, 4)
void gemm6464_kernel(const bf16* __restrict__ A, int lda, const bf16* __restrict__ B,
                     const float* __restrict__ bias, const TR* __restrict__ resid,
                     bf16* __restrict__ out, int M, int N, int K)
{
    __shared__ bf16 Al[2][64 * 64];
    __shared__ bf16 Bl[2][64 * 64];

    const int tid  = threadIdx.x;
    const int wave = tid >> 6;
    const int lane = tid & 63;
    const int l16  = lane & 15;
    const int quad = lane >> 4;
    int bx, by;
    xcd_swizzle2d(bx, by);
    const int bm   = by * 64;
    const int bn   = bx * 64;
    const int wm   = (wave >> 1) * 32;   // 0 or 32
    const int wn   = (wave & 1) * 32;    // 0 or 32
    const int lrow = lane >> 3;
    const int scol = ((lane & 7) ^ lrow) * 8;

    floatx4 acc[2][2] = {};
    const int ntk = K / 64;

    auto STAGE = [&](int kt, int buf) {
        const int k0 = kt * 64;
        #pragma unroll
        for (int i = 0; i < 2; ++i) {
            int r0 = wave * 16 + i * 8;
            gll16(A + (size_t)(bm + r0 + lrow) * lda + k0 + scol, &Al[buf][r0 * 64]);
            gll16(B + (size_t)(bn + r0 + lrow) * K   + k0 + scol, &Bl[buf][r0 * 64]);
        }
    };

    auto COMPUTE = [&](int buf) {
        #pragma unroll
        for (int ks = 0; ks < 2; ++ks) {
            bf16x8 af[2], bg[2];
            const int xo = ((ks * 4 + quad) ^ (l16 & 7)) * 8;
            #pragma unroll
            for (int mt = 0; mt < 2; ++mt)
                af[mt] = *(const bf16x8*)(&Al[buf][(wm + mt * 16 + l16) * 64 + xo]);
            #pragma unroll
            for (int nt = 0; nt < 2; ++nt)
                bg[nt] = *(const bf16x8*)(&Bl[buf][(wn + nt * 16 + l16) * 64 + xo]);
            #pragma unroll
            for (int mt = 0; mt < 2; ++mt)
                #pragma unroll
                for (int nt = 0; nt < 2; ++nt)
                    acc[mt][nt] = MFMA16(af[mt], bg[nt], acc[mt][nt]);
        }
    };

    STAGE(0, 0);
    asm volatile("s_waitcnt vmcnt(0)" ::: "memory");
    __builtin_amdgcn_s_barrier();

    int cur = 0;
    for (int t = 0; t < ntk - 1; ++t) {
        STAGE(t + 1, cur ^ 1);
        COMPUTE(cur);
        asm volatile("s_waitcnt vmcnt(0) lgkmcnt(0)" ::: "memory");
        __builtin_amdgcn_s_barrier();
        cur ^= 1;
    }
    COMPUTE(cur);

    #pragma unroll
    for (int mt = 0; mt < 2; ++mt) {
        int row0 = bm + wm + mt * 16 + quad * 4;
        #pragma unroll
        for (int nt = 0; nt < 2; ++nt) {
            int col = bn + wn + nt * 16 + l16;
            float bv = bias[col];
            #pragma unroll
            for (int r = 0; r < 4; ++r) {
                float v = acc[mt][nt][r] + bv;
                size_t idx = (size_t)(row0 + r) * N + col;
                if (EPI == 1) v = fmaxf(v, 0.0f);
                if (EPI == 2) v += loadf(resid + idx);
                out[idx] = (bf16)v;
            }
        }
    }
}

// ---------------- fused flash attention v3 ----------------
template <int CAUSAL>
__global__ __launch_bounds__(256, 3)
void attn_kernel(const bf16* __restrict__ Q, int ldq, const bf16* __restrict__ K, int ldk,
                 const bf16* __restrict__ Vt, bf16* __restrict__ O, int ldo)
{
    __shared__ bf16 Kl[2][64 * 64];   // [kv][d]
    __shared__ bf16 Vl[2][64 * 64];   // [d][kv] (from pre-transposed V)
    __shared__ bf16 Pl[4 * 16 * 72];  // per-wave P [q][kv]

    const int tid  = threadIdx.x;
    const int wave = tid >> 6;
    const int lane = tid & 63;
    const int l16  = lane & 15;
    const int quad = lane >> 4;
    int bx, byy, bz;
    {
        const int lin = (blockIdx.z * 16 + blockIdx.y) * 16 + blockIdx.x;
        const int swz = (lin & 7) * 128 + (lin >> 3);
        bx  = swz & 15;
        byy = (swz >> 4) & 15;
        bz  = swz >> 8;
    }
    const int qb   = CAUSAL ? (15 - bx) : bx;   // LPT for causal
    const int h    = byy;
    const int b    = bz;

    const int qrow0 = b * TT + qb * 64 + wave * 16;
    const int colh  = h * DH;
    const int lr8   = lane >> 3;
    const int lc8s  = ((lane & 7) ^ lr8) * 8;

    bf16x8 qa[2];
    #pragma unroll
    for (int c = 0; c < 2; ++c)
        qa[c] = *(const bf16x8*)(Q + (size_t)(qrow0 + l16) * ldq + colh + c * 32 + quad * 8);

    floatx4 o[5] = {};
    const float C = 0.125f * 1.4426950408889634f;
    bf16x8 onesf;
    {
        bf16 ov = (bf16)((l16 == 0) ? 1.0f : 0.0f);
        #pragma unroll
        for (int j = 0; j < 8; ++j) onesf[j] = ov;
    }

    const int ntiles = CAUSAL ? qb + 1 : (SS / 64);
    bf16* pw = Pl + wave * (16 * 72);

    auto STAGE = [&](int t, int buf) {
        const int kv0 = t * 64;
        #pragma unroll
        for (int i = 0; i < 2; ++i) {
            int r0 = wave * 16 + i * 8;
            gll16(K  + (size_t)(b * SS + kv0 + r0 + lr8) * ldk + colh + lc8s, &Kl[buf][r0 * 64]);
            gll16(Vt + (size_t)(colh + r0 + lr8) * MTOT + b * SS + kv0 + lc8s, &Vl[buf][r0 * 64]);
        }
    };

    auto COMPUTE = [&](int t, int buf) {
        const int xo0 = (quad ^ (l16 & 7)) * 8;
        const int xo1 = ((4 + quad) ^ (l16 & 7)) * 8;

        floatx4 s[4];
        #pragma unroll
        for (int nt = 0; nt < 4; ++nt) {
            bf16x8 kb0 = *(const bf16x8*)(&Kl[buf][(nt * 16 + l16) * 64 + xo0]);
            bf16x8 kb1 = *(const bf16x8*)(&Kl[buf][(nt * 16 + l16) * 64 + xo1]);
            floatx4 z = {};
            z = MFMA16(qa[0], kb0, z);
            z = MFMA16(qa[1], kb1, z);
            s[nt] = z;
        }

        const bool dm = CAUSAL && (t == qb);
        #pragma unroll
        for (int nt = 0; nt < 4; ++nt)
            #pragma unroll
            for (int r = 0; r < 4; ++r) {
                float sv = s[nt][r] * C;
                if (dm) {
                    int qg  = wave * 16 + quad * 4 + r;
                    int kvg = nt * 16 + l16;
                    if (kvg > qg) sv = -1e30f;
                }
                float pv = exp2f(sv);
                pw[(quad * 4 + r) * 72 + nt * 16 + l16] = (bf16)pv;
            }

        bf16x8 pa0 = *(const bf16x8*)(pw + l16 * 72 + quad * 8);
        bf16x8 pa1 = *(const bf16x8*)(pw + l16 * 72 + 32 + quad * 8);
        #pragma unroll
        for (int dt = 0; dt < 4; ++dt) {
            bf16x8 vb0 = *(const bf16x8*)(&Vl[buf][(dt * 16 + l16) * 64 + xo0]);
            bf16x8 vb1 = *(const bf16x8*)(&Vl[buf][(dt * 16 + l16) * 64 + xo1]);
            o[dt] = MFMA16(pa0, vb0, o[dt]);
            o[dt] = MFMA16(pa1, vb1, o[dt]);
        }
        o[4] = MFMA16(pa0, onesf, o[4]);
        o[4] = MFMA16(pa1, onesf, o[4]);
    };

    STAGE(0, 0);
    asm volatile("s_waitcnt vmcnt(0)" ::: "memory");
    __builtin_amdgcn_s_barrier();

    int cur = 0;
    for (int t = 0; t < ntiles - 1; ++t) {
        STAGE(t + 1, cur ^ 1);
        COMPUTE(t, cur);
        asm volatile("s_waitcnt vmcnt(0) lgkmcnt(0)" ::: "memory");
        __builtin_amdgcn_s_barrier();
        cur ^= 1;
    }
    COMPUTE(ntiles - 1, cur);

    #pragma unroll
    for (int r = 0; r < 4; ++r) {
        float lr  = __shfl(o[4][r], (lane & 48));
        float inv = __builtin_amdgcn_rcpf(lr);
        #pragma unroll
        for (int dt = 0; dt < 4; ++dt) {
            float ov = o[dt][r] * inv;
            size_t idx = (size_t)(qrow0 + quad * 4 + r) * ldo + colh + dt * 16 + l16;
            O[idx] = (bf16)ov;
        }
    }
}

// ---------------- LayerNorm: rows of 1024, bf16 in -> TO out ----------------
template <typename TO>
__global__ __launch_bounds__(256)
void ln_kernel(const bf16* __restrict__ in, const float* __restrict__ g,
               const float* __restrict__ be, TO* __restrict__ out)
{
    const int row = blockIdx.x;
    const int tid = threadIdx.x;
    bf16x4 xv = *(const bf16x4*)(in + (size_t)row * DMOD + tid * 4);
    float x0 = (float)xv[0], x1 = (float)xv[1], x2 = (float)xv[2], x3 = (float)xv[3];

    float s = x0 + x1 + x2 + x3;
    #pragma unroll
    for (int off = 32; off >= 1; off >>= 1) s += __shfl_xor(s, off);
    __shared__ float red1[4];
    __shared__ float red2[4];
    const int wave = tid >> 6;
    if ((tid & 63) == 0) red1[wave] = s;
    __syncthreads();
    float mean = (red1[0] + red1[1] + red1[2] + red1[3]) * (1.0f / DMOD);

    float d0 = x0 - mean, d1 = x1 - mean, d2 = x2 - mean, d3 = x3 - mean;
    float sq = d0 * d0 + d1 * d1 + d2 * d2 + d3 * d3;
    #pragma unroll
    for (int off = 32; off >= 1; off >>= 1) sq += __shfl_xor(sq, off);
    if ((tid & 63) == 0) red2[wave] = sq;
    __syncthreads();
    float var = (red2[0] + red2[1] + red2[2] + red2[3]) * (1.0f / DMOD);
    float rs = rsqrtf(var + 1e-6f);

    int c = tid * 4;
    size_t o0 = (size_t)row * DMOD + c;
    out[o0 + 0] = (TO)(g[c + 0] * d0 * rs + be[c + 0]);
    out[o0 + 1] = (TO)(g[c + 1] * d1 * rs + be[c + 1]);
    out[o0 + 2] = (TO)(g[c + 2] * d2 * rs + be[c + 2]);
    out[o0 + 3] = (TO)(g[c + 3] * d3 * rs + be[c + 3]);
}

// ---------------- launch ----------------
extern "C" void kernel_launch(void* const* d_in, const int* in_sizes, int n_in,
                              void* d_out, int out_size, void* d_ws, size_t ws_size,
                              hipStream_t stream)
{
    const float* x   = (const float*)d_in[0];
    const float* enc = (const float*)d_in[1];
    const float* wq1 = (const float*)d_in[4];  const float* bq1 = (const float*)d_in[5];
    const float* wk1 = (const float*)d_in[6];  const float* bk1 = (const float*)d_in[7];
    const float* wv1 = (const float*)d_in[8];  const float* bv1 = (const float*)d_in[9];
    const float* wo1 = (const float*)d_in[10]; const float* bo1 = (const float*)d_in[11];
    const float* wq2 = (const float*)d_in[12]; const float* bq2 = (const float*)d_in[13];
    const float* wk2 = (const float*)d_in[14]; const float* bk2 = (const float*)d_in[15];
    const float* wv2 = (const float*)d_in[16]; const float* bv2 = (const float*)d_in[17];
    const float* wo2 = (const float*)d_in[18]; const float* bo2 = (const float*)d_in[19];
    const float* wh  = (const float*)d_in[20]; const float* bh  = (const float*)d_in[21];
    const float* wou = (const float*)d_in[22]; const float* bou = (const float*)d_in[23];
    const float* g1  = (const float*)d_in[24]; const float* be1 = (const float*)d_in[25];
    const float* g2  = (const float*)d_in[26]; const float* be2 = (const float*)d_in[27];
    const float* g3  = (const float*)d_in[28]; const float* be3 = (const float*)d_in[29];

    const int M = MTOT;
    const size_t MB = 1u << 20;
    dim3 blk(256);

    // ws layout (57 MiB peak) — proven:
    // [0,8M) WT  [8,9M) biasc  [9,17M) xb/h1/tmpb3  [17,25M) encb / Vt2 / (ffn 17-49)
    // [25,49M) qkv/kvb/tmpb2  [49,57M) Vt1 / tmpb1 / h2
    char* ws = (char*)d_ws;
    bf16*  WT    = (bf16*)(ws);
    float* biasc = (float*)(ws + 8 * MB);
    bf16*  xb    = (bf16*)(ws + 9 * MB);
    bf16*  h1    = (bf16*)(ws + 9 * MB);
    bf16*  tmpb3 = (bf16*)(ws + 9 * MB);
    bf16*  encb  = (bf16*)(ws + 17 * MB);
    bf16*  Vt2   = (bf16*)(ws + 17 * MB);
    bf16*  ffn   = (bf16*)(ws + 17 * MB);
    bf16*  qkv   = (bf16*)(ws + 25 * MB);
    bf16*  kvb   = qkv + (size_t)M * 1024;
    bf16*  tmpb2 = qkv + (size_t)M * 1024;
    bf16*  Vt1   = (bf16*)(ws + 49 * MB);
    bf16*  tmpb1 = (bf16*)(ws + 49 * MB);
    bf16*  h2    = (bf16*)(ws + 49 * MB);

    dim3 gThi(HID / 64, DMOD / 64);
    dim3 gTout(DMOD / 64, HID / 64);
    dim3 gVt(DMOD / 64, M / 64);       // 16 x 64 for V-part transposes
    dim3 gQKV(3072 / 128, M / 64);     // 24 x 64 = 1536 blocks (3/CU eff)
    dim3 gKV(2048 / 128, M / 64);      // 16 x 64 = 1024 blocks
    dim3 gH(HID / 128, M / 64);        // 32 x 64 = 2048 blocks
    dim3 gN6464(DMOD / 64, M / 64);    // 16 x 64 = 1024 blocks (4/CU)
    dim3 gA(TT / 64, NH, BB);          // 1024 blocks
    const size_t W1M = (size_t)1024 * 1024;

    // ---- pre-pass ----
    cvt_kernel<<<dim3(M * DMOD / 4 / 256), blk, 0, stream>>>(x, xb, M * DMOD / 4);
    cvt_kernel<<<dim3(M * DMOD / 4 / 256), blk, 0, stream>>>(enc, encb, M * DMOD / 4);
    bias_concat_kernel<<<dim3(20), blk, 0, stream>>>(bq1, bk1, bv1, bk2, bv2, biasc);

    // transpose self-attn weights: [0]=wq1,[1]=wk1,[2]=wv1,[3]=wo1
    {
        TBatch tb;
        tb.src[0] = wq1; tb.dst[0] = WT + 0 * W1M;
        tb.src[1] = wk1; tb.dst[1] = WT + 1 * W1M;
        tb.src[2] = wv1; tb.dst[2] = WT + 2 * W1M;
        tb.src[3] = wo1; tb.dst[3] = WT + 3 * W1M;
        tb.src[4] = tb.src[5] = tb.src[6] = tb.src[7] = wq1;
        tb.dst[4] = tb.dst[5] = tb.dst[6] = tb.dst[7] = WT;
        dim3 g4(16, 16, 4);
        transpose_sq_kernel<<<g4, blk, 0, stream>>>(tb);
    }

    // ---- self-attention ----
    gemm64_kernel<0, bf16><<<gQKV, blk, 0, stream>>>(xb, 1024, WT, biasc,
                                                     (const bf16*)nullptr, qkv, M, 3072, 1024);
    vtrans_kernel<<<gVt, blk, 0, stream>>>(qkv + 2048, 3072, Vt1);
    attn_kernel<1><<<gA, blk, 0, stream>>>(qkv, 3072, qkv + 1024, 3072, Vt1, qkv, 3072);
    gemm6464_kernel<2, float><<<gN6464, blk, 0, stream>>>(qkv, 3072, WT + 3 * W1M, bo1, x,
                                                          tmpb1, M, 1024, 1024);
    ln_kernel<bf16><<<dim3(M), blk, 0, stream>>>(tmpb1, g1, be1, h1);

    // transpose cross-attn weights: [0]=wq2,[1]=wk2,[2]=wv2,[3]=wo2
    {
        TBatch tb;
        tb.src[0] = wq2; tb.dst[0] = WT + 0 * W1M;
        tb.src[1] = wk2; tb.dst[1] = WT + 1 * W1M;
        tb.src[2] = wv2; tb.dst[2] = WT + 2 * W1M;
        tb.src[3] = wo2; tb.dst[3] = WT + 3 * W1M;
        tb.src[4] = tb.src[5] = tb.src[6] = tb.src[7] = wq2;
        tb.dst[4] = tb.dst[5] = tb.dst[6] = tb.dst[7] = WT;
        dim3 g4(16, 16, 4);
        transpose_sq_kernel<<<g4, blk, 0, stream>>>(tb);
    }

    // ---- cross-attention ----
    gemm6464_kernel<0, bf16><<<gN6464, blk, 0, stream>>>(h1, 1024, WT, bq2, (const bf16*)nullptr,
                                                         qkv, M, 1024, 1024);
    gemm64_kernel<0, bf16><<<gKV, blk, 0, stream>>>(encb, 1024, WT + 1 * W1M, biasc + 3072,
                                                    (const bf16*)nullptr, kvb, M, 2048, 1024);
    vtrans_kernel<<<gVt, blk, 0, stream>>>(kvb + 1024, 2048, Vt2);
    attn_kernel<0><<<gA, blk, 0, stream>>>(qkv, 1024, kvb, 2048, Vt2, qkv, 1024);
    gemm6464_kernel<2, bf16><<<gN6464, blk, 0, stream>>>(qkv, 1024, WT + 3 * W1M, bo2, h1,
                                                         tmpb2, M, 1024, 1024);
    ln_kernel<bf16><<<dim3(M), blk, 0, stream>>>(tmpb2, g2, be2, h2);

    // ---- FFN ----
    transpose_kernel<<<gThi, blk, 0, stream>>>(wh, WT, DMOD, HID);
    gemm64_kernel<1, bf16><<<gH, blk, 0, stream>>>(h2, 1024, WT, bh, (const bf16*)nullptr,
                                                   ffn, M, HID, 1024);
    transpose_kernel<<<gTout, blk, 0, stream>>>(wou, WT, HID, DMOD);
    gemm6464_kernel<2, bf16><<<gN6464, blk, 0, stream>>>(ffn, 4096, WT, bou, h2,
                                                         tmpb3, M, 1024, 4096);
    ln_kernel<float><<<dim3(M), blk, 0, stream>>>(tmpb3, g3, be3, (float*)d_out);
}

// Round 10
// 500.911 us; speedup vs baseline: 1.0596x; 1.0596x over previous
//
#include <hip/hip_runtime.h>
#include <hip/hip_bf16.h>

typedef __bf16 bf16;
typedef __bf16 bf16x4 __attribute__((ext_vector_type(4)));
typedef __bf16 bf16x8 __attribute__((ext_vector_type(8)));
typedef float floatx4 __attribute__((ext_vector_type(4)));

#define MFMA16(a, b, c) __builtin_amdgcn_mfma_f32_16x16x32_bf16(a, b, c, 0, 0, 0)

// ---------------- constants ----------------
#define BB   4
#define TT   1024
#define SS   1024
#define DMOD 1024
#define NH   16
#define DH   64
#define HID  4096
#define MTOT (BB * TT)

__device__ __forceinline__ float loadf(const bf16* p)  { return (float)*p; }
__device__ __forceinline__ float loadf(const float* p) { return *p; }

// async global->LDS, 16B per lane; LDS dest = wave-uniform base + lane*16
__device__ __forceinline__ void gll16(const bf16* g, bf16* l) {
    __builtin_amdgcn_global_load_lds(
        (const __attribute__((address_space(1))) void*)g,
        (__attribute__((address_space(3))) void*)l, 16, 0, 0);
}

// XCD-chunked swizzle (T1): each XCD gets a contiguous chunk of the linear
// grid (y-major). Bijective iff nwg % 8 == 0 (all our grids satisfy this).
__device__ __forceinline__ void xcd_swizzle2d(int& bx, int& by) {
    const int gx  = gridDim.x;
    const int nwg = gx * gridDim.y;
    const int lin = blockIdx.y * gx + blockIdx.x;
    const int q   = nwg >> 3;
    const int swz = (lin & 7) * q + (lin >> 3);
    bx = swz % gx;
    by = swz / gx;
}

// ---------------- batched square transpose: fp32 W[1024][1024] -> bf16 WT ----------
struct TBatch { const float* src[8]; bf16* dst[8]; };

__global__ __launch_bounds__(256)
void transpose_sq_kernel(TBatch tb)
{
    __shared__ float t[64][65];
    const float* W = tb.src[blockIdx.z];
    bf16* WT = tb.dst[blockIdx.z];
    const int k0 = blockIdx.y * 64, n0 = blockIdx.x * 64;
    const int tid = threadIdx.x;
    const int r = tid >> 4, c = (tid & 15) * 4;
    #pragma unroll
    for (int i = 0; i < 4; ++i) {
        float4 v = *(const float4*)(W + (size_t)(k0 + i * 16 + r) * DMOD + n0 + c);
        t[i * 16 + r][c + 0] = v.x; t[i * 16 + r][c + 1] = v.y;
        t[i * 16 + r][c + 2] = v.z; t[i * 16 + r][c + 3] = v.w;
    }
    __syncthreads();
    #pragma unroll
    for (int i = 0; i < 4; ++i) {
        int n = i * 16 + r;
        bf16x4 o;
        #pragma unroll
        for (int j = 0; j < 4; ++j) o[j] = (bf16)t[c + j][n];
        *(bf16x4*)(WT + (size_t)(n0 + n) * DMOD + k0 + c) = o;
    }
}

// general transpose (for wh / wout)
__global__ __launch_bounds__(256)
void transpose_kernel(const float* __restrict__ W, bf16* __restrict__ WT, int K, int N)
{
    __shared__ float t[64][65];
    const int k0 = blockIdx.y * 64, n0 = blockIdx.x * 64;
    const int tid = threadIdx.x;
    const int r = tid >> 4, c = (tid & 15) * 4;
    #pragma unroll
    for (int i = 0; i < 4; ++i) {
        float4 v = *(const float4*)(W + (size_t)(k0 + i * 16 + r) * N + n0 + c);
        t[i * 16 + r][c + 0] = v.x; t[i * 16 + r][c + 1] = v.y;
        t[i * 16 + r][c + 2] = v.z; t[i * 16 + r][c + 3] = v.w;
    }
    __syncthreads();
    #pragma unroll
    for (int i = 0; i < 4; ++i) {
        int n = i * 16 + r;
        bf16x4 o;
        #pragma unroll
        for (int j = 0; j < 4; ++j) o[j] = (bf16)t[c + j][n];
        *(bf16x4*)(WT + (size_t)(n0 + n) * K + k0 + c) = o;
    }
}

// ---------------- bf16 sub-matrix transpose: in[4096][1024 cols](ldi) -> out[1024][4096]
__global__ __launch_bounds__(256)
void vtrans_kernel(const bf16* __restrict__ in, int ldi, bf16* __restrict__ out)
{
    __shared__ bf16 t[64][72];
    const int r0 = blockIdx.y * 64;   // M dim
    const int c0 = blockIdx.x * 64;   // col dim (1024)
    const int tid = threadIdx.x;
    const int rr = tid >> 3;          // 0..31
    const int c8 = (tid & 7) * 8;
    #pragma unroll
    for (int i = 0; i < 2; ++i) {
        int row = i * 32 + rr;
        bf16x8 v = *(const bf16x8*)(in + (size_t)(r0 + row) * ldi + c0 + c8);
        *(bf16x8*)(&t[row][c8]) = v;
    }
    __syncthreads();
    #pragma unroll
    for (int i = 0; i < 2; ++i) {
        int col = i * 32 + rr;
        bf16x8 v;
        #pragma unroll
        for (int j = 0; j < 8; ++j) v[j] = t[c8 + j][col];
        *(bf16x8*)(out + (size_t)(c0 + col) * MTOT + r0 + c8) = v;
    }
}

// ---------------- fp32 -> bf16 convert ----------------
__global__ __launch_bounds__(256)
void cvt_kernel(const float* __restrict__ in, bf16* __restrict__ out, int n4)
{
    int i = blockIdx.x * 256 + threadIdx.x;
    if (i < n4) {
        float4 v = ((const float4*)in)[i];
        bf16x4 o = { (bf16)v.x, (bf16)v.y, (bf16)v.z, (bf16)v.w };
        ((bf16x4*)out)[i] = o;
    }
}

// ---------------- bias concat: [bq1|bk1|bv1 | bk2|bv2] ----------------
__global__ __launch_bounds__(256)
void bias_concat_kernel(const float* bq1, const float* bk1, const float* bv1,
                        const float* bk2, const float* bv2, float* __restrict__ biasc)
{
    int i = blockIdx.x * 256 + threadIdx.x;   // 0..5119
    float v;
    if      (i < 1024) v = bq1[i];
    else if (i < 2048) v = bk1[i - 1024];
    else if (i < 3072) v = bv1[i - 2048];
    else if (i < 4096) v = bk2[i - 3072];
    else               v = bv2[i - 4096];
    if (i < 5120) biasc[i] = v;
}

// ------- GEMM 128x128, BK=32: wide-N GEMMs (QKV/KV/FFN1).
// BK=32 halves LDS to 32 KB -> 4 blocks/CU (16 waves/CU) at UNCHANGED traffic
// (staged bytes per matrix = BM*K / BN*K independent of BK). r9 lesson: BM/BN
// shrinking pays traffic; BK shrinking is free. 2-phase + T1 + chunk swizzle.
// Swizzle (64B rows, 4 chunks): store src chunk ^= (row>>1)&3; read
// xo = (quad ^ ((l16>>1)&3))*8 -> uniform 2-way banks (free, m136).
template <int EPI, typename TR>
__global__ __launch_bounds__(256, 4)
void gemm128k32_kernel(const bf16* __restrict__ A, int lda, const bf16* __restrict__ B,
                       const float* __restrict__ bias, const TR* __restrict__ resid,
                       bf16* __restrict__ out, int M, int N, int K)
{
    __shared__ bf16 Al[2][128 * 32];
    __shared__ bf16 Bl[2][128 * 32];

    const int tid  = threadIdx.x;
    const int wave = tid >> 6;
    const int lane = tid & 63;
    const int l16  = lane & 15;
    const int quad = lane >> 4;
    int bx, by;
    xcd_swizzle2d(bx, by);
    const int bm   = by * 128;
    const int bn   = bx * 128;
    const int wm   = (wave >> 1) * 64;
    const int wn   = (wave & 1) * 64;
    const int lrow = lane >> 2;                          // 0..15 (4 lanes/row, 64B rows)
    const int scol = ((lane & 3) ^ ((lane >> 3) & 3)) * 8;  // swizzled source chunk

    floatx4 acc[4][4] = {};
    const int ntk = K / 32;

    // stage 128x32 A and B tiles: 2 slabs of 16 rows per wave per matrix
    auto STAGE = [&](int kt, int buf) {
        const int k0 = kt * 32;
        #pragma unroll
        for (int i = 0; i < 2; ++i) {
            int r0 = (wave * 2 + i) * 16;
            gll16(A + (size_t)(bm + r0 + lrow) * lda + k0 + scol, &Al[buf][r0 * 32]);
            gll16(B + (size_t)(bn + r0 + lrow) * K   + k0 + scol, &Bl[buf][r0 * 32]);
        }
    };

    auto COMPUTE = [&](int buf) {
        bf16x8 af[4], bg[4];
        const int xo = ((quad ^ ((l16 >> 1) & 3))) * 8;
        #pragma unroll
        for (int mt = 0; mt < 4; ++mt)
            af[mt] = *(const bf16x8*)(&Al[buf][(wm + mt * 16 + l16) * 32 + xo]);
        #pragma unroll
        for (int nt = 0; nt < 4; ++nt)
            bg[nt] = *(const bf16x8*)(&Bl[buf][(wn + nt * 16 + l16) * 32 + xo]);
        #pragma unroll
        for (int mt = 0; mt < 4; ++mt)
            #pragma unroll
            for (int nt = 0; nt < 4; ++nt)
                acc[mt][nt] = MFMA16(af[mt], bg[nt], acc[mt][nt]);
    };

    STAGE(0, 0);
    asm volatile("s_waitcnt vmcnt(0)" ::: "memory");
    __builtin_amdgcn_s_barrier();

    int cur = 0;
    for (int t = 0; t < ntk - 1; ++t) {
        STAGE(t + 1, cur ^ 1);
        COMPUTE(cur);
        asm volatile("s_waitcnt vmcnt(0) lgkmcnt(0)" ::: "memory");
        __builtin_amdgcn_s_barrier();
        cur ^= 1;
    }
    COMPUTE(cur);

    #pragma unroll
    for (int mt = 0; mt < 4; ++mt) {
        int row0 = bm + wm + mt * 16 + quad * 4;
        #pragma unroll
        for (int nt = 0; nt < 4; ++nt) {
            int col = bn + wn + nt * 16 + l16;
            float bv = bias[col];
            #pragma unroll
            for (int r = 0; r < 4; ++r) {
                float v = acc[mt][nt][r] + bv;
                size_t idx = (size_t)(row0 + r) * N + col;
                if (EPI == 1) v = fmaxf(v, 0.0f);
                if (EPI == 2) v += loadf(resid + idx);
                out[idx] = (bf16)v;
            }
        }
    }
}

// ------- GEMM 64x64: N=1024 GEMMs + FFN2 (r7-proven: 4 blocks/CU TLP) -------
template <int EPI, typename TR>
__global__ __launch_bounds__(256, 4)
void gemm6464_kernel(const bf16* __restrict__ A, int lda, const bf16* __restrict__ B,
                     const float* __restrict__ bias, const TR* __restrict__ resid,
                     bf16* __restrict__ out, int M, int N, int K)
{
    __shared__ bf16 Al[2][64 * 64];
    __shared__ bf16 Bl[2][64 * 64];

    const int tid  = threadIdx.x;
    const int wave = tid >> 6;
    const int lane = tid & 63;
    const int l16  = lane & 15;
    const int quad = lane >> 4;
    int bx, by;
    xcd_swizzle2d(bx, by);
    const int bm   = by * 64;
    const int bn   = bx * 64;
    const int wm   = (wave >> 1) * 32;   // 0 or 32
    const int wn   = (wave & 1) * 32;    // 0 or 32
    const int lrow = lane >> 3;
    const int scol = ((lane & 7) ^ lrow) * 8;

    floatx4 acc[2][2] = {};
    const int ntk = K / 64;

    auto STAGE = [&](int kt, int buf) {
        const int k0 = kt * 64;
        #pragma unroll
        for (int i = 0; i < 2; ++i) {
            int r0 = wave * 16 + i * 8;
            gll16(A + (size_t)(bm + r0 + lrow) * lda + k0 + scol, &Al[buf][r0 * 64]);
            gll16(B + (size_t)(bn + r0 + lrow) * K   + k0 + scol, &Bl[buf][r0 * 64]);
        }
    };

    auto COMPUTE = [&](int buf) {
        #pragma unroll
        for (int ks = 0; ks < 2; ++ks) {
            bf16x8 af[2], bg[2];
            const int xo = ((ks * 4 + quad) ^ (l16 & 7)) * 8;
            #pragma unroll
            for (int mt = 0; mt < 2; ++mt)
                af[mt] = *(const bf16x8*)(&Al[buf][(wm + mt * 16 + l16) * 64 + xo]);
            #pragma unroll
            for (int nt = 0; nt < 2; ++nt)
                bg[nt] = *(const bf16x8*)(&Bl[buf][(wn + nt * 16 + l16) * 64 + xo]);
            #pragma unroll
            for (int mt = 0; mt < 2; ++mt)
                #pragma unroll
                for (int nt = 0; nt < 2; ++nt)
                    acc[mt][nt] = MFMA16(af[mt], bg[nt], acc[mt][nt]);
        }
    };

    STAGE(0, 0);
    asm volatile("s_waitcnt vmcnt(0)" ::: "memory");
    __builtin_amdgcn_s_barrier();

    int cur = 0;
    for (int t = 0; t < ntk - 1; ++t) {
        STAGE(t + 1, cur ^ 1);
        COMPUTE(cur);
        asm volatile("s_waitcnt vmcnt(0) lgkmcnt(0)" ::: "memory");
        __builtin_amdgcn_s_barrier();
        cur ^= 1;
    }
    COMPUTE(cur);

    #pragma unroll
    for (int mt = 0; mt < 2; ++mt) {
        int row0 = bm + wm + mt * 16 + quad * 4;
        #pragma unroll
        for (int nt = 0; nt < 2; ++nt) {
            int col = bn + wn + nt * 16 + l16;
            float bv = bias[col];
            #pragma unroll
            for (int r = 0; r < 4; ++r) {
                float v = acc[mt][nt][r] + bv;
                size_t idx = (size_t)(row0 + r) * N + col;
                if (EPI == 1) v = fmaxf(v, 0.0f);
                if (EPI == 2) v += loadf(resid + idx);
                out[idx] = (bf16)v;
            }
        }
    }
}

// ---------------- fused flash attention v3 ----------------
template <int CAUSAL>
__global__ __launch_bounds__(256, 3)
void attn_kernel(const bf16* __restrict__ Q, int ldq, const bf16* __restrict__ K, int ldk,
                 const bf16* __restrict__ Vt, bf16* __restrict__ O, int ldo)
{
    __shared__ bf16 Kl[2][64 * 64];   // [kv][d]
    __shared__ bf16 Vl[2][64 * 64];   // [d][kv] (from pre-transposed V)
    __shared__ bf16 Pl[4 * 16 * 72];  // per-wave P [q][kv]

    const int tid  = threadIdx.x;
    const int wave = tid >> 6;
    const int lane = tid & 63;
    const int l16  = lane & 15;
    const int quad = lane >> 4;
    int bx, byy, bz;
    {
        const int lin = (blockIdx.z * 16 + blockIdx.y) * 16 + blockIdx.x;
        const int swz = (lin & 7) * 128 + (lin >> 3);
        bx  = swz & 15;
        byy = (swz >> 4) & 15;
        bz  = swz >> 8;
    }
    const int qb   = CAUSAL ? (15 - bx) : bx;   // LPT for causal
    const int h    = byy;
    const int b    = bz;

    const int qrow0 = b * TT + qb * 64 + wave * 16;
    const int colh  = h * DH;
    const int lr8   = lane >> 3;
    const int lc8s  = ((lane & 7) ^ lr8) * 8;

    bf16x8 qa[2];
    #pragma unroll
    for (int c = 0; c < 2; ++c)
        qa[c] = *(const bf16x8*)(Q + (size_t)(qrow0 + l16) * ldq + colh + c * 32 + quad * 8);

    floatx4 o[5] = {};
    const float C = 0.125f * 1.4426950408889634f;
    bf16x8 onesf;
    {
        bf16 ov = (bf16)((l16 == 0) ? 1.0f : 0.0f);
        #pragma unroll
        for (int j = 0; j < 8; ++j) onesf[j] = ov;
    }

    const int ntiles = CAUSAL ? qb + 1 : (SS / 64);
    bf16* pw = Pl + wave * (16 * 72);

    auto STAGE = [&](int t, int buf) {
        const int kv0 = t * 64;
        #pragma unroll
        for (int i = 0; i < 2; ++i) {
            int r0 = wave * 16 + i * 8;
            gll16(K  + (size_t)(b * SS + kv0 + r0 + lr8) * ldk + colh + lc8s, &Kl[buf][r0 * 64]);
            gll16(Vt + (size_t)(colh + r0 + lr8) * MTOT + b * SS + kv0 + lc8s, &Vl[buf][r0 * 64]);
        }
    };

    auto COMPUTE = [&](int t, int buf) {
        const int xo0 = (quad ^ (l16 & 7)) * 8;
        const int xo1 = ((4 + quad) ^ (l16 & 7)) * 8;

        floatx4 s[4];
        #pragma unroll
        for (int nt = 0; nt < 4; ++nt) {
            bf16x8 kb0 = *(const bf16x8*)(&Kl[buf][(nt * 16 + l16) * 64 + xo0]);
            bf16x8 kb1 = *(const bf16x8*)(&Kl[buf][(nt * 16 + l16) * 64 + xo1]);
            floatx4 z = {};
            z = MFMA16(qa[0], kb0, z);
            z = MFMA16(qa[1], kb1, z);
            s[nt] = z;
        }

        const bool dm = CAUSAL && (t == qb);
        #pragma unroll
        for (int nt = 0; nt < 4; ++nt)
            #pragma unroll
            for (int r = 0; r < 4; ++r) {
                float sv = s[nt][r] * C;
                if (dm) {
                    int qg  = wave * 16 + quad * 4 + r;
                    int kvg = nt * 16 + l16;
                    if (kvg > qg) sv = -1e30f;
                }
                float pv = exp2f(sv);
                pw[(quad * 4 + r) * 72 + nt * 16 + l16] = (bf16)pv;
            }

        bf16x8 pa0 = *(const bf16x8*)(pw + l16 * 72 + quad * 8);
        bf16x8 pa1 = *(const bf16x8*)(pw + l16 * 72 + 32 + quad * 8);
        #pragma unroll
        for (int dt = 0; dt < 4; ++dt) {
            bf16x8 vb0 = *(const bf16x8*)(&Vl[buf][(dt * 16 + l16) * 64 + xo0]);
            bf16x8 vb1 = *(const bf16x8*)(&Vl[buf][(dt * 16 + l16) * 64 + xo1]);
            o[dt] = MFMA16(pa0, vb0, o[dt]);
            o[dt] = MFMA16(pa1, vb1, o[dt]);
        }
        o[4] = MFMA16(pa0, onesf, o[4]);
        o[4] = MFMA16(pa1, onesf, o[4]);
    };

    STAGE(0, 0);
    asm volatile("s_waitcnt vmcnt(0)" ::: "memory");
    __builtin_amdgcn_s_barrier();

    int cur = 0;
    for (int t = 0; t < ntiles - 1; ++t) {
        STAGE(t + 1, cur ^ 1);
        COMPUTE(t, cur);
        asm volatile("s_waitcnt vmcnt(0) lgkmcnt(0)" ::: "memory");
        __builtin_amdgcn_s_barrier();
        cur ^= 1;
    }
    COMPUTE(ntiles - 1, cur);

    #pragma unroll
    for (int r = 0; r < 4; ++r) {
        float lr  = __shfl(o[4][r], (lane & 48));
        float inv = __builtin_amdgcn_rcpf(lr);
        #pragma unroll
        for (int dt = 0; dt < 4; ++dt) {
            float ov = o[dt][r] * inv;
            size_t idx = (size_t)(qrow0 + quad * 4 + r) * ldo + colh + dt * 16 + l16;
            O[idx] = (bf16)ov;
        }
    }
}

// ---------------- LayerNorm: rows of 1024, bf16 in -> TO out ----------------
template <typename TO>
__global__ __launch_bounds__(256)
void ln_kernel(const bf16* __restrict__ in, const float* __restrict__ g,
               const float* __restrict__ be, TO* __restrict__ out)
{
    const int row = blockIdx.x;
    const int tid = threadIdx.x;
    bf16x4 xv = *(const bf16x4*)(in + (size_t)row * DMOD + tid * 4);
    float x0 = (float)xv[0], x1 = (float)xv[1], x2 = (float)xv[2], x3 = (float)xv[3];

    float s = x0 + x1 + x2 + x3;
    #pragma unroll
    for (int off = 32; off >= 1; off >>= 1) s += __shfl_xor(s, off);
    __shared__ float red1[4];
    __shared__ float red2[4];
    const int wave = tid >> 6;
    if ((tid & 63) == 0) red1[wave] = s;
    __syncthreads();
    float mean = (red1[0] + red1[1] + red1[2] + red1[3]) * (1.0f / DMOD);

    float d0 = x0 - mean, d1 = x1 - mean, d2 = x2 - mean, d3 = x3 - mean;
    float sq = d0 * d0 + d1 * d1 + d2 * d2 + d3 * d3;
    #pragma unroll
    for (int off = 32; off >= 1; off >>= 1) sq += __shfl_xor(sq, off);
    if ((tid & 63) == 0) red2[wave] = sq;
    __syncthreads();
    float var = (red2[0] + red2[1] + red2[2] + red2[3]) * (1.0f / DMOD);
    float rs = rsqrtf(var + 1e-6f);

    int c = tid * 4;
    size_t o0 = (size_t)row * DMOD + c;
    out[o0 + 0] = (TO)(g[c + 0] * d0 * rs + be[c + 0]);
    out[o0 + 1] = (TO)(g[c + 1] * d1 * rs + be[c + 1]);
    out[o0 + 2] = (TO)(g[c + 2] * d2 * rs + be[c + 2]);
    out[o0 + 3] = (TO)(g[c + 3] * d3 * rs + be[c + 3]);
}

// ---------------- launch ----------------
extern "C" void kernel_launch(void* const* d_in, const int* in_sizes, int n_in,
                              void* d_out, int out_size, void* d_ws, size_t ws_size,
                              hipStream_t stream)
{
    const float* x   = (const float*)d_in[0];
    const float* enc = (const float*)d_in[1];
    const float* wq1 = (const float*)d_in[4];  const float* bq1 = (const float*)d_in[5];
    const float* wk1 = (const float*)d_in[6];  const float* bk1 = (const float*)d_in[7];
    const float* wv1 = (const float*)d_in[8];  const float* bv1 = (const float*)d_in[9];
    const float* wo1 = (const float*)d_in[10]; const float* bo1 = (const float*)d_in[11];
    const float* wq2 = (const float*)d_in[12]; const float* bq2 = (const float*)d_in[13];
    const float* wk2 = (const float*)d_in[14]; const float* bk2 = (const float*)d_in[15];
    const float* wv2 = (const float*)d_in[16]; const float* bv2 = (const float*)d_in[17];
    const float* wo2 = (const float*)d_in[18]; const float* bo2 = (const float*)d_in[19];
    const float* wh  = (const float*)d_in[20]; const float* bh  = (const float*)d_in[21];
    const float* wou = (const float*)d_in[22]; const float* bou = (const float*)d_in[23];
    const float* g1  = (const float*)d_in[24]; const float* be1 = (const float*)d_in[25];
    const float* g2  = (const float*)d_in[26]; const float* be2 = (const float*)d_in[27];
    const float* g3  = (const float*)d_in[28]; const float* be3 = (const float*)d_in[29];

    const int M = MTOT;
    const size_t MB = 1u << 20;
    dim3 blk(256);

    // ws layout (57 MiB peak) — proven:
    // [0,8M) WT  [8,9M) biasc  [9,17M) xb/h1/tmpb3  [17,25M) encb / Vt2 / (ffn 17-49)
    // [25,49M) qkv/kvb/tmpb2  [49,57M) Vt1 / tmpb1 / h2
    char* ws = (char*)d_ws;
    bf16*  WT    = (bf16*)(ws);
    float* biasc = (float*)(ws + 8 * MB);
    bf16*  xb    = (bf16*)(ws + 9 * MB);
    bf16*  h1    = (bf16*)(ws + 9 * MB);
    bf16*  tmpb3 = (bf16*)(ws + 9 * MB);
    bf16*  encb  = (bf16*)(ws + 17 * MB);
    bf16*  Vt2   = (bf16*)(ws + 17 * MB);
    bf16*  ffn   = (bf16*)(ws + 17 * MB);
    bf16*  qkv   = (bf16*)(ws + 25 * MB);
    bf16*  kvb   = qkv + (size_t)M * 1024;
    bf16*  tmpb2 = qkv + (size_t)M * 1024;
    bf16*  Vt1   = (bf16*)(ws + 49 * MB);
    bf16*  tmpb1 = (bf16*)(ws + 49 * MB);
    bf16*  h2    = (bf16*)(ws + 49 * MB);

    dim3 gThi(HID / 64, DMOD / 64);
    dim3 gTout(DMOD / 64, HID / 64);
    dim3 gVt(DMOD / 64, M / 64);       // 16 x 64 for V-part transposes
    dim3 gQKV(3072 / 128, M / 128);    // 24 x 32 = 768 blocks
    dim3 gKV(2048 / 128, M / 128);     // 16 x 32 = 512 blocks
    dim3 gH(HID / 128, M / 128);       // 32 x 32 = 1024 blocks (4/CU)
    dim3 gN6464(DMOD / 64, M / 64);    // 16 x 64 = 1024 blocks (4/CU)
    dim3 gA(TT / 64, NH, BB);          // 1024 blocks
    const size_t W1M = (size_t)1024 * 1024;

    // ---- pre-pass ----
    cvt_kernel<<<dim3(M * DMOD / 4 / 256), blk, 0, stream>>>(x, xb, M * DMOD / 4);
    cvt_kernel<<<dim3(M * DMOD / 4 / 256), blk, 0, stream>>>(enc, encb, M * DMOD / 4);
    bias_concat_kernel<<<dim3(20), blk, 0, stream>>>(bq1, bk1, bv1, bk2, bv2, biasc);

    // transpose self-attn weights: [0]=wq1,[1]=wk1,[2]=wv1,[3]=wo1
    {
        TBatch tb;
        tb.src[0] = wq1; tb.dst[0] = WT + 0 * W1M;
        tb.src[1] = wk1; tb.dst[1] = WT + 1 * W1M;
        tb.src[2] = wv1; tb.dst[2] = WT + 2 * W1M;
        tb.src[3] = wo1; tb.dst[3] = WT + 3 * W1M;
        tb.src[4] = tb.src[5] = tb.src[6] = tb.src[7] = wq1;
        tb.dst[4] = tb.dst[5] = tb.dst[6] = tb.dst[7] = WT;
        dim3 g4(16, 16, 4);
        transpose_sq_kernel<<<g4, blk, 0, stream>>>(tb);
    }

    // ---- self-attention ----
    gemm128k32_kernel<0, bf16><<<gQKV, blk, 0, stream>>>(xb, 1024, WT, biasc,
                                                         (const bf16*)nullptr, qkv, M, 3072, 1024);
    vtrans_kernel<<<gVt, blk, 0, stream>>>(qkv + 2048, 3072, Vt1);
    attn_kernel<1><<<gA, blk, 0, stream>>>(qkv, 3072, qkv + 1024, 3072, Vt1, qkv, 3072);
    gemm6464_kernel<2, float><<<gN6464, blk, 0, stream>>>(qkv, 3072, WT + 3 * W1M, bo1, x,
                                                          tmpb1, M, 1024, 1024);
    ln_kernel<bf16><<<dim3(M), blk, 0, stream>>>(tmpb1, g1, be1, h1);

    // transpose cross-attn weights: [0]=wq2,[1]=wk2,[2]=wv2,[3]=wo2
    {
        TBatch tb;
        tb.src[0] = wq2; tb.dst[0] = WT + 0 * W1M;
        tb.src[1] = wk2; tb.dst[1] = WT + 1 * W1M;
        tb.src[2] = wv2; tb.dst[2] = WT + 2 * W1M;
        tb.src[3] = wo2; tb.dst[3] = WT + 3 * W1M;
        tb.src[4] = tb.src[5] = tb.src[6] = tb.src[7] = wq2;
        tb.dst[4] = tb.dst[5] = tb.dst[6] = tb.dst[7] = WT;
        dim3 g4(16, 16, 4);
        transpose_sq_kernel<<<g4, blk, 0, stream>>>(tb);
    }

    // ---- cross-attention ----
    gemm6464_kernel<0, bf16><<<gN6464, blk, 0, stream>>>(h1, 1024, WT, bq2, (const bf16*)nullptr,
                                                         qkv, M, 1024, 1024);
    gemm128k32_kernel<0, bf16><<<gKV, blk, 0, stream>>>(encb, 1024, WT + 1 * W1M, biasc + 3072,
                                                        (const bf16*)nullptr, kvb, M, 2048, 1024);
    vtrans_kernel<<<gVt, blk, 0, stream>>>(kvb + 1024, 2048, Vt2);
    attn_kernel<0><<<gA, blk, 0, stream>>>(qkv, 1024, kvb, 2048, Vt2, qkv, 1024);
    gemm6464_kernel<2, bf16><<<gN6464, blk, 0, stream>>>(qkv, 1024, WT + 3 * W1M, bo2, h1,
                                                         tmpb2, M, 1024, 1024);
    ln_kernel<bf16><<<dim3(M), blk, 0, stream>>>(tmpb2, g2, be2, h2);

    // ---- FFN ----
    transpose_kernel<<<gThi, blk, 0, stream>>>(wh, WT, DMOD, HID);
    gemm128k32_kernel<1, bf16><<<gH, blk, 0, stream>>>(h2, 1024, WT, bh, (const bf16*)nullptr,
                                                       ffn, M, HID, 1024);
    transpose_kernel<<<gTout, blk, 0, stream>>>(wou, WT, HID, DMOD);
    gemm6464_kernel<2, bf16><<<gN6464, blk, 0, stream>>>(ffn, 4096, WT, bou, h2,
                                                         tmpb3, M, 1024, 4096);
    ln_kernel<float><<<dim3(M), blk, 0, stream>>>(tmpb3, g3, be3, (float*)d_out);
}